// Round 3
// baseline (2786.354 us; speedup 1.0000x reference)
//
#include <hip/hip_runtime.h>

// PolicyAwareLSTM: 2-layer LSTM (4096 x 336, 32->64->32) + seq1-MHA (== two 32x32
// matmuls) + dense 32->64->24 head. fp32 throughout (no fp32 MFMA on CDNA4).
//
// R3: replace the split-K partial reduction through LDS (zp round-trip: 32 b128
// writes + 24 b128 reads per wave-step ~= 90% DS-pipe occupancy, the R2 limiter)
// with in-wave DPP butterfly adds (VALU pipe, zero LDS traffic).
//  - L1: tid = 8*u + kg  -> 8 K-split partners are lanes 8u..8u+7 (same wave).
//    3-stage butterfly: quad_perm xor1 (0xB1), quad_perm xor2 (0x4E),
//    row_half_mirror (0x141). Lane kg==r keeps row r (cndmask select).
//  - L2: tid = 16*u2 + kg2, 4-stage butterfly (+ row_mirror 0x140).
//  - Gate nonlinearities now run on all 512 threads (thread = one row-unit).
//  - act rows padded to 132 floats: h1/h2/x writes and all phase reads are
//    conflict-free or natural 2-way (free).
//  - 3 barriers/step (was 4); LDS 69.6KB -> ~8.5KB.

#define B_TOTAL 4096
#define T_STEPS 336
#define NF      32     // input features
#define U1N     64     // layer-1 units
#define G1      256    // 4*U1N
#define U2N     32     // layer-2 units
#define G2      128    // 4*U2N
#define RROWS   8      // batch rows per block
#define NT      512    // threads per block
#define KH1     12     // L1 K-slice (8 k-groups x 12 = 96)
#define KH2     6      // L2 K-slice (16 k-groups x 6 = 96)
#define APAD    132    // padded activation row stride (kills bank conflicts)

__device__ __forceinline__ float fast_sigmoid(float x) {
    return __fdividef(1.0f, 1.0f + __expf(-x));
}

__device__ __forceinline__ float fast_tanh(float x) {
    float ax = fabsf(x);
    float e  = __expf(-2.0f * ax);
    float r  = __fdividef(1.0f - e, 1.0f + e);
    return __builtin_copysignf(r, x);
}

template<int CTRL>
__device__ __forceinline__ float dpp_add_f(float v) {
    return v + __int_as_float(
        __builtin_amdgcn_mov_dpp(__float_as_int(v), CTRL, 0xF, 0xF, true));
}

// sum across 8-lane groups (lanes 8k..8k+7); all lanes receive the sum
__device__ __forceinline__ void red8(float4& z) {
    z.x = dpp_add_f<0xB1>(z.x);  z.y = dpp_add_f<0xB1>(z.y);
    z.z = dpp_add_f<0xB1>(z.z);  z.w = dpp_add_f<0xB1>(z.w);
    z.x = dpp_add_f<0x4E>(z.x);  z.y = dpp_add_f<0x4E>(z.y);
    z.z = dpp_add_f<0x4E>(z.z);  z.w = dpp_add_f<0x4E>(z.w);
    z.x = dpp_add_f<0x141>(z.x); z.y = dpp_add_f<0x141>(z.y);
    z.z = dpp_add_f<0x141>(z.z); z.w = dpp_add_f<0x141>(z.w);
}

// sum across 16-lane groups; all lanes receive the sum
__device__ __forceinline__ void red16(float4& z) {
    red8(z);
    z.x = dpp_add_f<0x140>(z.x); z.y = dpp_add_f<0x140>(z.y);
    z.z = dpp_add_f<0x140>(z.z); z.w = dpp_add_f<0x140>(z.w);
}

__global__ __launch_bounds__(NT) void lstm_fused(
    const float* __restrict__ x,
    const float* __restrict__ W1, const float* __restrict__ U1, const float* __restrict__ b1,
    const float* __restrict__ W2, const float* __restrict__ U2, const float* __restrict__ b2,
    const float* __restrict__ Wv, const float* __restrict__ bv,
    const float* __restrict__ Wo, const float* __restrict__ bo,
    const float* __restrict__ Wd1, const float* __restrict__ bd1,
    const float* __restrict__ Wd2, const float* __restrict__ bd2,
    float* __restrict__ out)
{
    __shared__ float act_sh[RROWS][APAD];   // [x(32) | h1(64) | h2(32)] (+pad)
    __shared__ float hb[1024];              // head scratch

    const int tid = threadIdx.x;
    const int r0  = blockIdx.x * RROWS;

    // ---- thread roles
    const int u1  = tid >> 3;               // L1 unit (0..63)
    const int kg1 = tid & 7;                // L1 k-group / final row owner
    const int u2  = tid >> 4;               // L2 unit (0..31)
    const int kg2 = tid & 15;               // L2 k-group
    const int pr  = tid >> 5, pu = tid & 31;// x-park & head row/col (tid<256)

    // ---- weights: 4 gate-columns of one unit, K-sliced
    float4 w1w[KH1];
    #pragma unroll
    for (int j = 0; j < KH1; ++j) {
        const int kk = KH1 * kg1 + j;       // 0..95 over [x(32)|h1(64)]
        const float* row = (kk < NF) ? (W1 + kk * G1) : (U1 + (kk - NF) * G1);
        w1w[j] = make_float4(row[u1], row[64 + u1], row[128 + u1], row[192 + u1]);
    }
    const float4 b1v = make_float4(b1[u1], b1[64 + u1], b1[128 + u1], b1[192 + u1]);

    float4 w2w[KH2];
    #pragma unroll
    for (int j = 0; j < KH2; ++j) {
        const int kk = KH2 * kg2 + j;       // 0..95 over [h1(64)|h2(32)]
        const float* row = (kk < U1N) ? (W2 + kk * G2) : (U2 + (kk - U1N) * G2);
        w2w[j] = make_float4(row[u2], row[32 + u2], row[64 + u2], row[96 + u2]);
    }
    const float4 b2v = make_float4(b2[u2], b2[32 + u2], b2[64 + u2], b2[96 + u2]);

    // ---- init: zero act, zero cell states, park x_0
    for (int i = tid; i < RROWS * APAD; i += NT) (&act_sh[0][0])[i] = 0.0f;
    float c1 = 0.f, c2 = 0.f;
    float4 zr1 = make_float4(0.f, 0.f, 0.f, 0.f);
    float4 zr2 = make_float4(0.f, 0.f, 0.f, 0.f);
    const int xbase = (r0 + pr) * (T_STEPS * NF) + pu;
    __syncthreads();
    if (tid < 256) act_sh[pr][pu] = x[xbase];
    __syncthreads();

    for (int t = 0; t < T_STEPS; ++t) {
        // prefetch next x slice (parked after B1)
        float xnext = 0.f;
        if (tid < 256) {
            const int tn = (t + 1 < T_STEPS) ? (t + 1) : (T_STEPS - 1);
            xnext = x[xbase + tn * NF];
        }

        // ---- phase 1: per row, 12-k FMA slice -> 8-lane butterfly -> keep row kg1
        {
            const int ab = KH1 * kg1;
            #pragma unroll
            for (int r = 0; r < RROWS; ++r) {
                const float4* av = reinterpret_cast<const float4*>(&act_sh[r][ab]);
                const float4 a0 = av[0], a1 = av[1], a2 = av[2];
                float a[KH1];
                a[0]=a0.x; a[1]=a0.y; a[2]=a0.z;  a[3]=a0.w;
                a[4]=a1.x; a[5]=a1.y; a[6]=a1.z;  a[7]=a1.w;
                a[8]=a2.x; a[9]=a2.y; a[10]=a2.z; a[11]=a2.w;
                float4 acc = make_float4(0.f, 0.f, 0.f, 0.f);
                #pragma unroll
                for (int j = 0; j < KH1; ++j) {
                    acc.x = fmaf(a[j], w1w[j].x, acc.x);
                    acc.y = fmaf(a[j], w1w[j].y, acc.y);
                    acc.z = fmaf(a[j], w1w[j].z, acc.z);
                    acc.w = fmaf(a[j], w1w[j].w, acc.w);
                }
                red8(acc);
                const bool keep = (kg1 == r);
                zr1.x = keep ? acc.x : zr1.x;
                zr1.y = keep ? acc.y : zr1.y;
                zr1.z = keep ? acc.z : zr1.z;
                zr1.w = keep ? acc.w : zr1.w;
            }
        }
        // gate 1 (registers only; write delayed past B1). Thread = (row kg1, unit u1).
        float h1v;
        {
            const float ig = fast_sigmoid(zr1.x + b1v.x);
            const float fg = fast_sigmoid(zr1.y + b1v.y);
            const float gg = fast_tanh   (zr1.z + b1v.z);
            const float og = fast_sigmoid(zr1.w + b1v.w);
            c1  = fmaf(fg, c1, ig * gg);
            h1v = og * fast_tanh(c1);
        }
        __syncthreads();                      // B1: all phase-1 act reads done
        act_sh[kg1][NF + u1] = h1v;
        if (tid < 256) act_sh[pr][pu] = xnext;
        __syncthreads();                      // B2: h1_t + x_{t+1} visible

        // ---- phase 2: per row, 6-k FMA slice -> 16-lane butterfly -> keep row kg2&7
        {
            const int ab = NF + KH2 * kg2;
            #pragma unroll
            for (int r = 0; r < RROWS; ++r) {
                const float2* av = reinterpret_cast<const float2*>(&act_sh[r][ab]);
                const float2 a0 = av[0], a1 = av[1], a2 = av[2];
                float a[KH2];
                a[0]=a0.x; a[1]=a0.y; a[2]=a1.x; a[3]=a1.y; a[4]=a2.x; a[5]=a2.y;
                float4 acc = make_float4(0.f, 0.f, 0.f, 0.f);
                #pragma unroll
                for (int j = 0; j < KH2; ++j) {
                    acc.x = fmaf(a[j], w2w[j].x, acc.x);
                    acc.y = fmaf(a[j], w2w[j].y, acc.y);
                    acc.z = fmaf(a[j], w2w[j].z, acc.z);
                    acc.w = fmaf(a[j], w2w[j].w, acc.w);
                }
                red16(acc);
                const bool keep = ((kg2 & 7) == r);
                zr2.x = keep ? acc.x : zr2.x;
                zr2.y = keep ? acc.y : zr2.y;
                zr2.z = keep ? acc.z : zr2.z;
                zr2.w = keep ? acc.w : zr2.w;
            }
        }
        // gate 2 (computed redundantly on lane twins kg2 and kg2+8)
        float h2v;
        {
            const float ig = fast_sigmoid(zr2.x + b2v.x);
            const float fg = fast_sigmoid(zr2.y + b2v.y);
            const float gg = fast_tanh   (zr2.z + b2v.z);
            const float og = fast_sigmoid(zr2.w + b2v.w);
            c2  = fmaf(fg, c2, ig * gg);
            h2v = og * fast_tanh(c2);
        }
        __syncthreads();                      // B3: all phase-2 act reads done
        if (kg2 < 8) act_sh[kg2][96 + u2] = h2v;
        // no 4th barrier: next phase-1 touches only act[.][0..96); next phase-2
        // reads h2 after B2(t+1), which orders this write.
    }
    __syncthreads();                          // h2_T visible for the head

    // ---- head: v = h2@Wv+bv ; o = v@Wo+bo ; d1 = relu(o@Wd1+bd1) ; out = d1@Wd2+bd2
    {
        if (tid < 256) {
            float acc = bv[pu];
            #pragma unroll
            for (int j = 0; j < 32; ++j) acc = fmaf(act_sh[pr][96 + j], Wv[j * 32 + pu], acc);
            hb[tid] = acc;                    // v[r][u]
        }
        __syncthreads();
        if (tid < 256) {
            float acc = bo[pu];
            #pragma unroll
            for (int j = 0; j < 32; ++j) acc = fmaf(hb[pr * 32 + j], Wo[j * 32 + pu], acc);
            hb[256 + tid] = acc;              // o[r][u]
        }
        __syncthreads();
        {
            const int dr = tid >> 6, dc = tid & 63;
            float acc = bd1[dc];
            #pragma unroll
            for (int j = 0; j < 32; ++j) acc = fmaf(hb[256 + dr * 32 + j], Wd1[j * 64 + dc], acc);
            hb[512 + tid] = fmaxf(acc, 0.f);  // d1[r][c]
        }
        __syncthreads();
        if (tid < RROWS * 24) {
            const int rr = tid / 24, cc = tid - rr * 24;
            float acc = bd2[cc];
            #pragma unroll
            for (int j = 0; j < 64; ++j) acc = fmaf(hb[512 + rr * 64 + j], Wd2[j * 24 + cc], acc);
            out[(r0 + rr) * 24 + cc] = acc;
        }
    }
}

extern "C" void kernel_launch(void* const* d_in, const int* in_sizes, int n_in,
                              void* d_out, int out_size, void* d_ws, size_t ws_size,
                              hipStream_t stream) {
    const float* x   = (const float*)d_in[0];
    const float* W1  = (const float*)d_in[1];
    const float* U1  = (const float*)d_in[2];
    const float* b1  = (const float*)d_in[3];
    const float* W2  = (const float*)d_in[4];
    const float* U2  = (const float*)d_in[5];
    const float* b2  = (const float*)d_in[6];
    // d_in[7..10] = Wq, bq, Wk, bk — dead: softmax over a length-1 axis is identically 1
    const float* Wv  = (const float*)d_in[11];
    const float* bv  = (const float*)d_in[12];
    const float* Wo  = (const float*)d_in[13];
    const float* bo  = (const float*)d_in[14];
    const float* Wd1 = (const float*)d_in[15];
    const float* bd1 = (const float*)d_in[16];
    const float* Wd2 = (const float*)d_in[17];
    const float* bd2 = (const float*)d_in[18];
    float* outp = (float*)d_out;

    hipLaunchKernelGGL(lstm_fused, dim3(B_TOTAL / RROWS), dim3(NT), 0, stream,
                       x, W1, U1, b1, W2, U2, b2, Wv, bv, Wo, bo,
                       Wd1, bd1, Wd2, bd2, outp);
}

// Round 4
// 1884.081 us; speedup vs baseline: 1.4789x; 1.4789x over previous
//
#include <hip/hip_runtime.h>

// PolicyAwareLSTM: 2-layer LSTM (4096 x 336, 32->64->32) + seq1-MHA (== two 32x32
// matmuls) + dense 32->64->24 head. fp32 throughout (no fp32 MFMA on CDNA4).
//
// R4 = R2 (best verified, 1933us) + __launch_bounds__(NT, 4). Single-variable
// experiment: R2's counters show VGPR_Count=64 with ~120 live floats needed and
// zero scratch traffic -> ~72 weight floats live in AGPRs (gfx90a+ spills to
// AGPR before scratch), costing one v_accvgpr_read per weight-FMA. That is
// +~576 VALU instr/step, matching the measured 10.0K VALU cycles/SIMD/step vs
// ~5.6K counted from source. launch_bounds(512,4) = min 4 waves/EU -> 128-VGPR
// budget (same 16 waves/CU residency as R2) so weights live in arch VGPRs.
// (R1's waves_per_eu(2,2) failed because max=2 capped occupancy without raising
// the allocator budget; R3's DPP butterfly failed pushing reduction onto VALU.)
//
// Structure (R2): 512 threads, 512 blocks, 2 blocks/CU.
//  - Gate-interleaved 4-cols/thread + K-split: thread owns the 4 gates (i,f,g,o)
//    of ONE unit over a K-slice (12 for L1, 6 for L2). Broadcast activation
//    reads feed 4 FMAs each; partial z stores / gate reads are float4.
//  - Unified activation row act[x(32)|h1(64)|h2(32)].
//  - zp partial buffer (64KB) shared between layers, reused as head scratch.

#define B_TOTAL 4096
#define T_STEPS 336
#define NF      32     // input features
#define U1N     64     // layer-1 units
#define G1      256    // 4*U1N
#define U2N     32     // layer-2 units
#define G2      128    // 4*U2N
#define RROWS   8      // batch rows per block
#define NT      512    // threads per block
#define KH1     12     // L1 K-slice (8 k-groups x 12 = 96)
#define KG1     8
#define KH2     6      // L2 K-slice (16 k-groups x 6 = 96)
#define KG2     16

__device__ __forceinline__ float fast_sigmoid(float x) {
    return __fdividef(1.0f, 1.0f + __expf(-x));
}

__device__ __forceinline__ float fast_tanh(float x) {
    float ax = fabsf(x);
    float e  = __expf(-2.0f * ax);
    float r  = __fdividef(1.0f - e, 1.0f + e);
    return __builtin_copysignf(r, x);
}

__global__ __launch_bounds__(NT, 4) void lstm_fused(
    const float* __restrict__ x,
    const float* __restrict__ W1, const float* __restrict__ U1, const float* __restrict__ b1,
    const float* __restrict__ W2, const float* __restrict__ U2, const float* __restrict__ b2,
    const float* __restrict__ Wv, const float* __restrict__ bv,
    const float* __restrict__ Wo, const float* __restrict__ bo,
    const float* __restrict__ Wd1, const float* __restrict__ bd1,
    const float* __restrict__ Wd2, const float* __restrict__ bd2,
    float* __restrict__ out)
{
    __shared__ float act_sh[RROWS][128];       // [x(32) | h1(64) | h2(32)] per row, 4KB
    __shared__ float zp[RROWS * KG1 * G1];     // 64KB: L1 partials [r][kg1][4u+g];
                                               // L2 partials [r][kg2][4u+g] (flat); head scratch

    const int tid = threadIdx.x;
    const int r0  = blockIdx.x * RROWS;

    // ---- thread roles
    const int ucol = tid & 63;                 // L1 unit (0..63)
    const int kg1  = tid >> 6;                 // L1 k-group (0..7)
    const int u2   = tid & 31;                 // L2 unit (0..31)
    const int kg2  = tid >> 5;                 // L2 k-group (0..15)
    const int g1r  = tid >> 6, g1u = tid & 63; // gate1 / d1 mapping (8r x 64u)
    const int g2r  = tid >> 5, g2u = tid & 31; // gate2 / x-park / head mapping (8r x 32u)

    // ---- weights: 4 gate-columns of one unit, K-sliced (load-time gather, coalesced in u)
    float4 w1w[KH1];
    #pragma unroll
    for (int j = 0; j < KH1; ++j) {
        const int kk = KH1 * kg1 + j;          // 0..95 over [x(32)|h1(64)]
        const float* row = (kk < NF) ? (W1 + kk * G1) : (U1 + (kk - NF) * G1);
        w1w[j] = make_float4(row[ucol], row[64 + ucol], row[128 + ucol], row[192 + ucol]);
    }
    float4 b1v = make_float4(0.f, 0.f, 0.f, 0.f);
    if (kg1 == 0)
        b1v = make_float4(b1[ucol], b1[64 + ucol], b1[128 + ucol], b1[192 + ucol]);

    float4 w2w[KH2];
    #pragma unroll
    for (int j = 0; j < KH2; ++j) {
        const int kk = KH2 * kg2 + j;          // 0..95 over [h1(64)|h2(32)]
        const float* row = (kk < U1N) ? (W2 + kk * G2) : (U2 + (kk - U1N) * G2);
        w2w[j] = make_float4(row[u2], row[32 + u2], row[64 + u2], row[96 + u2]);
    }
    float4 b2v = make_float4(0.f, 0.f, 0.f, 0.f);
    if (kg2 == 0)
        b2v = make_float4(b2[u2], b2[32 + u2], b2[64 + u2], b2[96 + u2]);

    // ---- init: zero act (x area overwritten below), zero cell states
    reinterpret_cast<float2*>(&act_sh[0][0])[tid] = make_float2(0.f, 0.f); // 1024 floats
    float c1 = 0.f, c2 = 0.f;

    const int xbase = (r0 + g2r) * (T_STEPS * NF) + g2u;   // x-park role: row g2r, feat g2u
    __syncthreads();
    if (tid < 256) act_sh[g2r][g2u] = x[xbase];            // x_0
    __syncthreads();

    for (int t = 0; t < T_STEPS; ++t) {
        // prefetch next x slice (issued early; parked after B1)
        float xnext = 0.f;
        if (tid < 256) {
            const int tn = (t + 1 < T_STEPS) ? (t + 1) : (T_STEPS - 1);
            xnext = x[xbase + tn * NF];
        }

        // ---- phase 1: z1 partials. Thread: unit ucol, gates i/f/g/o, k in [12*kg1, +12)
        {
            const int ab = KH1 * kg1;          // 16B-aligned (48B multiples)
            #pragma unroll
            for (int r = 0; r < RROWS; ++r) {
                const float4* av = reinterpret_cast<const float4*>(&act_sh[r][ab]);
                const float4 a0 = av[0], a1 = av[1], a2 = av[2];
                float a[KH1];
                a[0]=a0.x; a[1]=a0.y; a[2]=a0.z;  a[3]=a0.w;
                a[4]=a1.x; a[5]=a1.y; a[6]=a1.z;  a[7]=a1.w;
                a[8]=a2.x; a[9]=a2.y; a[10]=a2.z; a[11]=a2.w;
                float4 acc = b1v;
                #pragma unroll
                for (int j = 0; j < KH1; ++j) {
                    acc.x = fmaf(a[j], w1w[j].x, acc.x);
                    acc.y = fmaf(a[j], w1w[j].y, acc.y);
                    acc.z = fmaf(a[j], w1w[j].z, acc.z);
                    acc.w = fmaf(a[j], w1w[j].w, acc.w);
                }
                *reinterpret_cast<float4*>(&zp[(r * KG1 + kg1) * G1 + 4 * ucol]) = acc;
            }
        }
        __syncthreads();  // B1: zp(L1) ready; act reads of phase1 done

        // ---- gate 1: thread = (row g1r, unit g1u); sum 8 k-group partials (float4 reads)
        {
            float4 z = make_float4(0.f, 0.f, 0.f, 0.f);
            #pragma unroll
            for (int k = 0; k < KG1; ++k) {
                const float4 p = *reinterpret_cast<const float4*>(&zp[(g1r * KG1 + k) * G1 + 4 * g1u]);
                z.x += p.x; z.y += p.y; z.z += p.z; z.w += p.w;
            }
            const float ig = fast_sigmoid(z.x);
            const float fg = fast_sigmoid(z.y);
            const float gg = fast_tanh(z.z);
            const float og = fast_sigmoid(z.w);
            c1 = fmaf(fg, c1, ig * gg);
            act_sh[g1r][NF + g1u] = og * fast_tanh(c1);     // h1_t
            if (tid < 256) act_sh[g2r][g2u] = xnext;        // park x_{t+1}
        }
        __syncthreads();  // B2: h1_t visible; zp(L1) reads done

        // ---- phase 2: z2 partials. Thread: unit u2, k in act-coords [32+6*kg2, +6)
        {
            const int ab = NF + KH2 * kg2;     // 8B-aligned
            #pragma unroll
            for (int r = 0; r < RROWS; ++r) {
                const float2* av = reinterpret_cast<const float2*>(&act_sh[r][ab]);
                const float2 a0 = av[0], a1 = av[1], a2 = av[2];
                float a[KH2];
                a[0]=a0.x; a[1]=a0.y; a[2]=a1.x; a[3]=a1.y; a[4]=a2.x; a[5]=a2.y;
                float4 acc = b2v;
                #pragma unroll
                for (int j = 0; j < KH2; ++j) {
                    acc.x = fmaf(a[j], w2w[j].x, acc.x);
                    acc.y = fmaf(a[j], w2w[j].y, acc.y);
                    acc.z = fmaf(a[j], w2w[j].z, acc.z);
                    acc.w = fmaf(a[j], w2w[j].w, acc.w);
                }
                *reinterpret_cast<float4*>(&zp[(r * KG2 + kg2) * G2 + 4 * u2]) = acc;
            }
        }
        __syncthreads();  // B3: zp(L2) ready; act reads of phase2 done

        // ---- gate 2: tid<256 = (row g2r, unit g2u); sum 16 k-group partials
        if (tid < 256) {
            float4 z = make_float4(0.f, 0.f, 0.f, 0.f);
            #pragma unroll
            for (int k = 0; k < KG2; ++k) {
                const float4 p = *reinterpret_cast<const float4*>(&zp[(g2r * KG2 + k) * G2 + 4 * g2u]);
                z.x += p.x; z.y += p.y; z.z += p.z; z.w += p.w;
            }
            const float ig = fast_sigmoid(z.x);
            const float fg = fast_sigmoid(z.y);
            const float gg = fast_tanh(z.z);
            const float og = fast_sigmoid(z.w);
            c2 = fmaf(fg, c2, ig * gg);
            act_sh[g2r][96 + g2u] = og * fast_tanh(c2);     // h2_t
        }
        __syncthreads();  // B4: zp free for next phase1; h2_t visible
    }

    // ---- head: v = h2@Wv+bv ; o = v@Wo+bo ; d1 = relu(o@Wd1+bd1) ; out = d1@Wd2+bd2
    {
        float* hb = &zp[0];                    // scratch: v[0..256), o[256..512), d1[512..1024)
        if (tid < 256) {
            float acc = bv[g2u];
            #pragma unroll
            for (int j = 0; j < 32; ++j) acc = fmaf(act_sh[g2r][96 + j], Wv[j * 32 + g2u], acc);
            hb[tid] = acc;                     // v[r][u]
        }
        __syncthreads();
        if (tid < 256) {
            float acc = bo[g2u];
            #pragma unroll
            for (int j = 0; j < 32; ++j) acc = fmaf(hb[g2r * 32 + j], Wo[j * 32 + g2u], acc);
            hb[256 + tid] = acc;               // o[r][u]
        }
        __syncthreads();
        {
            // d1: all 512 threads, (row g1r, col g1u)
            float acc = bd1[g1u];
            #pragma unroll
            for (int j = 0; j < 32; ++j) acc = fmaf(hb[256 + g1r * 32 + j], Wd1[j * 64 + g1u], acc);
            hb[512 + tid] = fmaxf(acc, 0.f);   // d1[r][c]
        }
        __syncthreads();
        if (tid < RROWS * 24) {
            const int rr = tid / 24, cc = tid - rr * 24;
            float acc = bd2[cc];
            #pragma unroll
            for (int j = 0; j < 64; ++j) acc = fmaf(hb[512 + rr * 64 + j], Wd2[j * 24 + cc], acc);
            out[(r0 + rr) * 24 + cc] = acc;
        }
    }
}

extern "C" void kernel_launch(void* const* d_in, const int* in_sizes, int n_in,
                              void* d_out, int out_size, void* d_ws, size_t ws_size,
                              hipStream_t stream) {
    const float* x   = (const float*)d_in[0];
    const float* W1  = (const float*)d_in[1];
    const float* U1  = (const float*)d_in[2];
    const float* b1  = (const float*)d_in[3];
    const float* W2  = (const float*)d_in[4];
    const float* U2  = (const float*)d_in[5];
    const float* b2  = (const float*)d_in[6];
    // d_in[7..10] = Wq, bq, Wk, bk — dead: softmax over a length-1 axis is identically 1
    const float* Wv  = (const float*)d_in[11];
    const float* bv  = (const float*)d_in[12];
    const float* Wo  = (const float*)d_in[13];
    const float* bo  = (const float*)d_in[14];
    const float* Wd1 = (const float*)d_in[15];
    const float* bd1 = (const float*)d_in[16];
    const float* Wd2 = (const float*)d_in[17];
    const float* bd2 = (const float*)d_in[18];
    float* outp = (float*)d_out;

    hipLaunchKernelGGL(lstm_fused, dim3(B_TOTAL / RROWS), dim3(NT), 0, stream,
                       x, W1, U1, b1, W2, U2, b2, Wv, bv, Wo, bo,
                       Wd1, bd1, Wd2, bd2, outp);
}